// Round 3
// baseline (192.933 us; speedup 1.0000x reference)
//
#include <hip/hip_runtime.h>
#include <hip/hip_bf16.h>
#include <math.h>

#define N_NODES 50000
#define N_EDGES 600000
#define D_IN 256
#define D_GNN 128
#define CAP 32        // padded adjacency slots per node (ushort); 1 cache line
#define MAX_OVER 8192
#define EB_STRIDE 264 // epilogue LDS bf16 row stride (256 + 8 pad)

typedef short s16x8 __attribute__((ext_vector_type(8)));
typedef float f32x4 __attribute__((ext_vector_type(4)));

__device__ __forceinline__ unsigned short f2bf(float f) {
  unsigned int u = __float_as_uint(f);
  u += 0x7FFFu + ((u >> 16) & 1u);  // RNE
  return (unsigned short)(u >> 16);
}

// ---------------------------------------------------------------------------
// Prologue: zero cursor[] + overflow count + pack Wc=[W_l|W_r] to B-fragment
// order (bf16): Wcp[((ks*256+col)*4+q)*8+j] = [Wl|Wr][ks*32+q*8+j][col]
// ---------------------------------------------------------------------------
__global__ __launch_bounds__(256) void pack0(
    const float* __restrict__ Wl, const float* __restrict__ Wr,
    ushort* __restrict__ Wcp, int* __restrict__ cursor,
    int* __restrict__ ovcnt) {
  int i = blockIdx.x * 256 + threadIdx.x;
  if (i < N_NODES) cursor[i] = 0;
  if (i == 0) ovcnt[0] = 0;
  if (i < 8192) {  // one 16B B-fragment per thread
    int q = i & 3, col = (i >> 2) & 255, ks = i >> 10;
    const float* W = (col < 128) ? Wl : Wr;
    int c = col & 127;
    int k0 = ks * 32 + q * 8;
    s16x8 v;
#pragma unroll
    for (int j = 0; j < 8; j++) v[j] = (short)f2bf(W[(k0 + j) * D_GNN + c]);
    *((s16x8*)(Wcp + (size_t)i * 8)) = v;
  }
}

// ---------------------------------------------------------------------------
// FUSED kernel (R3): LDS-free MFMA GEMM + edge scatter.
//   Theory: R0 (reg-staged) and R1 (async gload_lds) both measured 43-44us ->
//   staging mechanism irrelevant; wall = concurrency depth (2 blocks/CU,
//   serial stage->vmcnt(0)->compute chain). Fix: A-fragments are 8 contiguous
//   k-elems of one row = two float4 loads DIRECT from x (16 full lines per
//   instr; 4 waves share rows via L1). No staging LDS, no staging barrier.
//   Block = 16 rows x 256 cols, 256 thr, 4 waves; 6 blocks/CU resident.
//   Edge work: ei loaded at start (coalesced); atomic+colp scatter issued
//   after the K-loop so its latency hides under the epilogue barrier and
//   drains across block boundaries. colp is ushort: one node row = 1 line.
// ---------------------------------------------------------------------------
__global__ __launch_bounds__(256, 6) void fused_gemm_fill(
    const float* __restrict__ x, const ushort* __restrict__ Wcp,
    const float* __restrict__ b_l, const int* __restrict__ ei,
    int* __restrict__ cursor, ushort* __restrict__ colp,
    int* __restrict__ ovcnt, int2* __restrict__ over,
    ushort* __restrict__ yb, ushort* __restrict__ yrb) {
  __shared__ ushort eb[16 * EB_STRIDE];  // 8448 B epilogue transpose buffer
  const int t = threadIdx.x;
  const int n0 = blockIdx.x * 16;        // 3125 blocks * 16 = 50000 exactly
  const int l = t & 63;
  const int w = t >> 6;                  // wave = col group (64 cols)
  const int lq = l >> 4, l16 = l & 15;

  // --- early edge load (<=1 edge/thread; 3125*256 = 800256 >= N_EDGES) ---
  const int e = blockIdx.x * 256 + t;
  int esrc = 0, edst = 0;
  const bool has_e = (e < N_EDGES);
  if (has_e) {
    esrc = ei[e];
    edst = ei[N_EDGES + e];
  }

  // --- A row pointer: lane (l16,lq) holds x[n0+l16][ks*32 + lq*8 .. +8) ---
  int row = n0 + l16;
  if (row >= N_NODES) row = N_NODES - 1;  // never true (50000%16==0); safety
  const float* arow = x + (size_t)row * D_IN + lq * 8;

  const ushort* bptr[4];
#pragma unroll
  for (int ct = 0; ct < 4; ct++) {
    int col = w * 64 + ct * 16 + l16;
    bptr[ct] = Wcp + ((size_t)col * 4 + lq) * 8;
  }

  f32x4 acc[4];
#pragma unroll
  for (int ct = 0; ct < 4; ct++) acc[ct] = (f32x4){0.f, 0.f, 0.f, 0.f};

#pragma unroll
  for (int ks = 0; ks < 8; ks++) {
    float4 a0 = *((const float4*)(arow + ks * 32));
    float4 a1 = *((const float4*)(arow + ks * 32 + 4));
    union { s16x8 v; ushort4 u[2]; } ua;
    __hip_bfloat162 h0 = __float22bfloat162_rn(make_float2(a0.x, a0.y));
    __hip_bfloat162 h1 = __float22bfloat162_rn(make_float2(a0.z, a0.w));
    __hip_bfloat162 h2 = __float22bfloat162_rn(make_float2(a1.x, a1.y));
    __hip_bfloat162 h3 = __float22bfloat162_rn(make_float2(a1.z, a1.w));
    ua.u[0].x = ((ushort2*)&h0)->x; ua.u[0].y = ((ushort2*)&h0)->y;
    ua.u[0].z = ((ushort2*)&h1)->x; ua.u[0].w = ((ushort2*)&h1)->y;
    ua.u[1].x = ((ushort2*)&h2)->x; ua.u[1].y = ((ushort2*)&h2)->y;
    ua.u[1].z = ((ushort2*)&h3)->x; ua.u[1].w = ((ushort2*)&h3)->y;
    s16x8 A = ua.v;
#pragma unroll
    for (int ct = 0; ct < 4; ct++) {
      s16x8 B = *((const s16x8*)(bptr[ct] + (size_t)ks * 8192));
      acc[ct] = __builtin_amdgcn_mfma_f32_16x16x32_bf16(A, B, acc[ct], 0, 0, 0);
    }
  }

  // --- edge scatter: atomic issued now; pos-dependent store later so its
  //     waitcnt overlaps the eb writes + barrier ---
  int pos = -1;
  if (has_e) pos = atomicAdd(&cursor[edst], 1);

  // --- acc -> LDS bf16 (C/D layout: col=lane&15, row=lq*4+reg) ---
#pragma unroll
  for (int ct = 0; ct < 4; ct++) {
    int col = w * 64 + ct * 16 + l16;  // 0..255
    float bias = (col >= 128) ? b_l[col - 128] : 0.f;
#pragma unroll
    for (int r = 0; r < 4; r++) {
      eb[(lq * 4 + r) * EB_STRIDE + col] = f2bf(acc[ct][r] + bias);
    }
  }

  if (pos >= 0) {
    if (pos < CAP) {
      colp[edst * CAP + pos] = (ushort)esrc;
    } else {
      int o = atomicAdd(ovcnt, 1);
      if (o < MAX_OVER) over[o] = make_int2(edst, esrc);
    }
  }

  __syncthreads();

  // --- vectorized stores: 16 rows x 256 cols x 2B = 512 x 16B chunks ---
#pragma unroll
  for (int p = 0; p < 2; p++) {
    int id = p * 256 + t;       // 0..511
    int rl = id >> 5;           // 0..15
    int c8 = (id & 31) * 8;     // 0..248
    int gn = n0 + rl;
    if (gn < N_NODES) {
      s16x8 v = *((const s16x8*)(eb + rl * EB_STRIDE + c8));
      if (c8 < 128)
        *((s16x8*)(yb + (size_t)gn * D_GNN + c8)) = v;
      else
        *((s16x8*)(yrb + (size_t)gn * D_GNN + (c8 - 128))) = v;
    }
  }
}

// ---------------------------------------------------------------------------
// Gather (padded adjacency, ushort cols) + epilogue + pred head. One wave per
// node; lane owns dims {2*lane, 2*lane+1}. True degree = cursor[node]; first
// min(deg,CAP) neighbors in colp[node*CAP..] (one 64B line), rest in the
// exact overflow list (wave-uniform scan, expected ~0 entries).
// ---------------------------------------------------------------------------
__global__ __launch_bounds__(256) void gather_pred(
    const int* __restrict__ cursor, const ushort* __restrict__ colp,
    const int* __restrict__ ovcnt, const int2* __restrict__ over,
    const ushort* __restrict__ yb, const ushort* __restrict__ yrb,
    const float* __restrict__ Wfc, const float* __restrict__ bfc,
    float* __restrict__ h, float* __restrict__ pred) {
  const int node = (blockIdx.x * 256 + threadIdx.x) >> 6;
  const int lane = threadIdx.x & 63;
  if (node >= N_NODES) return;
  const int degt = cursor[node];
  const int m = min(degt, CAP);
  float ax = 0.f, ay = 0.f;
  const unsigned int* y32 = (const unsigned int*)yb;

  int c = (lane < m) ? (int)colp[node * CAP + lane] : 0;
  int j = 0;
  for (; j + 4 <= m; j += 4) {
    int s0 = __shfl(c, j), s1 = __shfl(c, j + 1);
    int s2 = __shfl(c, j + 2), s3 = __shfl(c, j + 3);
    unsigned int v0 = y32[(size_t)s0 * 64 + lane];
    unsigned int v1 = y32[(size_t)s1 * 64 + lane];
    unsigned int v2 = y32[(size_t)s2 * 64 + lane];
    unsigned int v3 = y32[(size_t)s3 * 64 + lane];
    ax += __uint_as_float(v0 << 16) + __uint_as_float(v1 << 16) +
          __uint_as_float(v2 << 16) + __uint_as_float(v3 << 16);
    ay += __uint_as_float(v0 & 0xFFFF0000u) + __uint_as_float(v1 & 0xFFFF0000u) +
          __uint_as_float(v2 & 0xFFFF0000u) + __uint_as_float(v3 & 0xFFFF0000u);
  }
  for (; j < m; j++) {
    int s0 = __shfl(c, j);
    unsigned int v0 = y32[(size_t)s0 * 64 + lane];
    ax += __uint_as_float(v0 << 16);
    ay += __uint_as_float(v0 & 0xFFFF0000u);
  }
  if (degt > CAP) {  // exact overflow handling (rare; wave-uniform)
    int nov = min(ovcnt[0], MAX_OVER);
    for (int k = 0; k < nov; k++) {
      int2 ov = over[k];
      if (ov.x == node) {
        unsigned int v0 = y32[(size_t)ov.y * 64 + lane];
        ax += __uint_as_float(v0 << 16);
        ay += __uint_as_float(v0 & 0xFFFF0000u);
      }
    }
  }

  const float ic = degt > 0 ? 1.f / (float)degt : 0.f;
  unsigned int yrv = ((const unsigned int*)yrb)[(size_t)node * 64 + lane];
  float h0 = ax * ic + __uint_as_float(yrv << 16);
  float h1 = ay * ic + __uint_as_float(yrv & 0xFFFF0000u);
  float2 hv; hv.x = h0; hv.y = h1;
  ((float2*)h)[(size_t)node * 64 + lane] = hv;
  float s = h0 * Wfc[2 * lane] + h1 * Wfc[2 * lane + 1];
#pragma unroll
  for (int off = 32; off > 0; off >>= 1) s += __shfl_down(s, off);
  if (lane == 0) pred[node] = 1.f / (1.f + expf(-(s + bfc[0])));
}

extern "C" void kernel_launch(void* const* d_in, const int* in_sizes, int n_in,
                              void* d_out, int out_size, void* d_ws,
                              size_t ws_size, hipStream_t stream) {
  const float* x   = (const float*)d_in[0];
  const int*   ei  = (const int*)d_in[1];
  const float* Wl  = (const float*)d_in[2];
  const float* bl  = (const float*)d_in[3];
  const float* Wr  = (const float*)d_in[4];
  const float* Wfc = (const float*)d_in[5];
  const float* bfc = (const float*)d_in[6];

  float* out  = (float*)d_out;
  float* h    = out;                        // [N,128] final h (f32)
  float* pred = out + (size_t)N_NODES * D_GNN;

  ushort* Wcp   = (ushort*)d_ws;                              // 128 KB
  ushort* yb    = Wcp + 8192 * 8;                             // [N,128] bf16
  ushort* yrb   = yb + (size_t)N_NODES * D_GNN;               // [N,128] bf16
  int*   cursor = (int*)(yrb + (size_t)N_NODES * D_GNN);      // [N]
  int*   ovcnt  = cursor + N_NODES;                           // [1]
  int2*  over   = (int2*)(ovcnt + 1);                         // [MAX_OVER]
  ushort* colp  = (ushort*)(over + MAX_OVER);                 // [N*CAP] ushort

  // --- prologue: zero cursor/ovcnt + pack W ---
  pack0<<<(N_NODES + 255) / 256, 256, 0, stream>>>(Wl, Wr, Wcp, cursor, ovcnt);

  // --- fused: LDS-free GEMM + adjacency scatter (background drain) ---
  fused_gemm_fill<<<(N_NODES + 15) / 16, 256, 0, stream>>>(
      x, Wcp, bl, ei, cursor, colp, ovcnt, over, yb, yrb);

  // --- mean gather + h epilogue + pred head ---
  gather_pred<<<(N_NODES * 64 + 255) / 256, 256, 0, stream>>>(
      cursor, colp, ovcnt, over, yb, yrb, Wfc, bfc, h, pred);
}